// Round 8
// baseline (463.118 us; speedup 1.0000x reference)
//
#include <hip/hip_runtime.h>

#define N_SAMP   1024
#define IN_F     512
#define OUT_F    512
#define N_HEADS  32
#define N_SPLITS 4
#define N_GROUPS (N_HEADS * N_SPLITS)
#define DELTA_SCALE 0.1f

// R13: R12 (fused + nt-D + nt-store, < 79 us verified) scaled from 16 to 32
// waves/CU -- the CU maximum -- with ZERO change to the per-wave memory
// pattern. Same 1024-block grid (8 col-tiles x 128 combos), but 512-thread
// blocks: thread = (c2 0..31, kq 0..15), KQ=16, KT=32, NST=8.
//
// Evidence: unique-byte supply scaled with resident waves across rounds
// (8 waves/CU -> 1.7 TB/s [R10]; 16 -> 3.2-3.5 TB/s [R7/R12]) while
// request width, row geometry, and XCD pinning were each falsified as
// drivers. That is a per-wave latency-throughput limit; this kernel has
// never run above 16 waves/CU (grid 1024 = 4 blocks/CU x 4 waves).
// 4 blocks/CU x 8 waves = 32 waves/CU. LDS 36.9 KB unchanged (fits 4/CU);
// logical traffic unchanged; no duplication. Red epilogue runs in two
// j-halves (Red[16][8][32] f2 = 32 KB aliases the 32 KB Xs buffer).
// VGPR must stay <=64 for 8 waves/SIMD: launch_bounds(512, 8) (was 56).

typedef float f32x2 __attribute__((ext_vector_type(2)));

__device__ __forceinline__ f32x2 nt_load2(const float* p) {
    return __builtin_nontemporal_load((const f32x2*)p);
}
__device__ __forceinline__ void nt_store2(float* p, f32x2 v) {
    __builtin_nontemporal_store(v, (f32x2*)p);
}

__global__ __launch_bounds__(512, 8) void lms_fused_nt512(
    const float* __restrict__ X, const int* __restrict__ head_ix,
    const int* __restrict__ split_ix, const float* __restrict__ W,
    const float* __restrict__ D, const float* __restrict__ bias,
    float* __restrict__ out)
{
    constexpr int J    = 16;           // samples per chunk
    constexpr int KQ   = 16;           // k-split ways
    constexpr int KT   = IN_F / KQ;    // 32 k rows per thread
    constexpr int NST  = KT / 4;       // 8 steps of 4 rows

    __shared__ float buf[J * IN_F];    // Xs[16][512] <-> Red[16][8][32] f2
    __shared__ int   list[N_SAMP];
    __shared__ int   wsum[8];

    const int g    = blockIdx.y;           // combo = h*N_SPLITS + s
    const int h    = g >> 2;               // N_SPLITS == 4
    const int c0   = blockIdx.x * 64;
    const int tid  = threadIdx.x;
    const int c2   = tid & 31;             // col pair
    const int kq   = tid >> 5;             // k-sixteenth (0..15)
    const int lane = tid & 63;
    const int wave = tid >> 6;             // 0..7

    // deterministic order-preserving compaction of samples matching combo g
    int run = 0;
    for (int r = 0; r < N_SAMP / 512; ++r) {   // 2 rounds
        const int i   = r * 512 + tid;
        const int key = head_ix[i] * N_SPLITS + split_ix[i];
        const bool hit = (key == g);
        const unsigned long long m = __ballot(hit);
        if (lane == 0) wsum[wave] = __popcll(m);
        __syncthreads();
        int base = run;
#pragma unroll
        for (int w = 0; w < 8; ++w)
            if (w < wave) base += wsum[w];
        if (hit)
            list[base + __popcll(m & ((1ULL << lane) - 1ULL))] = i;
        int rs = 0;
#pragma unroll
        for (int w = 0; w < 8; ++w) rs += wsum[w];
        run += rs;
        __syncthreads();               // wsum consumed before next round
    }
    const int total = run;
    if (total == 0) return;            // block-uniform

    // thread's stripes: rows kq*KT .. kq*KT+31, cols c0+2*c2 (+1)
    const size_t roff = (size_t)(kq * KT) * OUT_F + c0 + c2 * 2;
    const float* wp = W + (size_t)h * (IN_F * OUT_F) + roff;
    const float* dp = D + (size_t)g * (IN_F * OUT_F) + roff;

    for (int s0 = 0; s0 < total; s0 += J) {
        const int nc = min(total - s0, J);

        __syncthreads();               // buf may still hold previous Red
        // stage Xs: 2048 float4 over 512 threads = 4 each
#pragma unroll
        for (int f = 0; f < 4; ++f) {
            const int i = f * 512 + tid;       // 0..2047
            const int s = i >> 7, q = i & 127;
            float4 v = make_float4(0.f, 0.f, 0.f, 0.f);
            if (s < nc)
                v = *(const float4*)(X + (size_t)list[s0 + s] * IN_F + q * 4);
            *(float4*)(&buf[s * IN_F + q * 4]) = v;
        }
        __syncthreads();

        float2 acc[J];
#pragma unroll
        for (int j = 0; j < J; ++j) { acc[j].x = 0.f; acc[j].y = 0.f; }

        // distance-1 double-buffered 4-row batches: W cached, D nontemporal
        float2 wb[2][4];
        f32x2  db[2][4];
#pragma unroll
        for (int u = 0; u < 4; ++u) {
            wb[0][u] = *(const float2*)(wp + (size_t)u * OUT_F);
            db[0][u] = nt_load2(dp + (size_t)u * OUT_F);
        }

#pragma unroll 2
        for (int st = 0; st < NST; ++st) {
            // prefetch next 4-row batch (clamped tail keeps body branch-free)
            const int nx = (st + 1 < NST) ? st + 1 : NST - 1;
            const int nb = (st + 1) & 1, cb = st & 1;
            const float* wn = wp + (size_t)(nx * 4) * OUT_F;
            const float* dn = dp + (size_t)(nx * 4) * OUT_F;
#pragma unroll
            for (int u = 0; u < 4; ++u) {
                wb[nb][u] = *(const float2*)(wn + (size_t)u * OUT_F);
                db[nb][u] = nt_load2(dn + (size_t)u * OUT_F);
            }

            // combined weight for this 4-row batch
            float2 rc[4];
#pragma unroll
            for (int u = 0; u < 4; ++u) {
                rc[u].x = wb[cb][u].x + DELTA_SCALE * db[cb][u].x;
                rc[u].y = wb[cb][u].y + DELTA_SCALE * db[cb][u].y;
            }

            const float* xb = &buf[kq * KT + st * 4];
#pragma unroll
            for (int j = 0; j < J; ++j) {
                const float4 xv = *(const float4*)(xb + j * IN_F); // broadcast
                acc[j].x += xv.x * rc[0].x; acc[j].y += xv.x * rc[0].y;
                acc[j].x += xv.y * rc[1].x; acc[j].y += xv.y * rc[1].y;
                acc[j].x += xv.z * rc[2].x; acc[j].y += xv.z * rc[2].y;
                acc[j].x += xv.w * rc[3].x; acc[j].y += xv.w * rc[3].y;
            }
        }

        // k-reduction + store, in two j-halves (Red[16][8][32] f2 = 32 KB
        // aliases buf). Xs fully consumed by the step loop above.
        float2* Red = (float2*)buf;
#pragma unroll
        for (int hf = 0; hf < 2; ++hf) {
            __syncthreads();           // buf free (Xs / previous Red reads done)
#pragma unroll
            for (int jj = 0; jj < 8; ++jj)
                Red[(kq * 8 + jj) * 32 + c2] = acc[hf * 8 + jj];
            __syncthreads();
            if (tid < 256) {
                const int j  = tid >> 5;       // 0..7
                const int cc = tid & 31;
                const int js = hf * 8 + j;
                if (js < nc) {
                    float2 s = make_float2(0.f, 0.f);
#pragma unroll
                    for (int q = 0; q < KQ; ++q) {
                        const float2 r = Red[(q * 8 + j) * 32 + cc];
                        s.x += r.x; s.y += r.y;
                    }
                    const float2 bv =
                        *(const float2*)(bias + (size_t)h * OUT_F + c0 + cc * 2);
                    float* op = out + (size_t)list[s0 + js] * OUT_F + c0 + cc * 2;
                    f32x2 res;
                    res.x = s.x + bv.x;
                    res.y = s.y + bv.y;
                    nt_store2(op, res);
                }
            }
        }
    }
}

extern "C" void kernel_launch(void* const* d_in, const int* in_sizes, int n_in,
                              void* d_out, int out_size, void* d_ws, size_t ws_size,
                              hipStream_t stream) {
    const float* X        = (const float*)d_in[0];
    const int*   head_ix  = (const int*)d_in[1];
    const int*   split_ix = (const int*)d_in[2];
    const float* W        = (const float*)d_in[3];
    const float* D        = (const float*)d_in[4];
    const float* bias     = (const float*)d_in[5];
    float*       out      = (float*)d_out;

    // 128 combos x 8 col-tiles = 1024 blocks of 512 threads = 4 blocks/CU
    // x 8 waves = 32 waves/CU (CU max). LDS 36.9 KB -> 4/CU; VGPR capped
    // at 64 by launch_bounds(512,8). Single dispatch; out written once.
    dim3 gf(OUT_F / 64, N_GROUPS);
    lms_fused_nt512<<<gf, 512, 0, stream>>>(X, head_ix, split_ix, W, D, bias, out);
}

// Round 9
// 308.346 us; speedup vs baseline: 1.5019x; 1.5019x over previous
//
#include <hip/hip_runtime.h>

#define N_SAMP   1024
#define IN_F     512
#define OUT_F    512
#define N_HEADS  32
#define N_SPLITS 4
#define N_GROUPS (N_HEADS * N_SPLITS)
#define DELTA_SCALE 0.1f

// R14: clean 32-waves/CU test. R13 failed because __launch_bounds__ arg2 is
// WORKGROUPS/CU on this toolchain (R13 (512,8) -> 16 waves/SIMD -> 32-VGPR
// cap -> 455 MB spill traffic; R7/R10/R12 register counts all consistent
// with this decode). Wave-scaling (8->16 waves/CU doubled supply) is still
// unfalsified and R13's 69% occupancy shows the machinery works.
//
// Only col-tiles raise blocks/CU without duplicating W/D register traffic
// (every block streams its whole stripe into registers regardless of J, so
// sg-splits double demand and cancel the wave gain -- R8's lesson).
//
//   grid = 16 col-tiles x 128 combos = 2048 blocks of 256 thr
//        = 8 blocks/CU x 4 waves = 32 waves/CU (CU max).
//   thread = (c2 = tid&15: col pair in 32-col tile, kq = tid>>4: KQ=16,
//   KT=32, NST=8). J=8 (mean combo = 8 samples -> 1 chunk typical).
//   launch_bounds(256,8) -> VGPR cap 64; J=8 acc halves R12's 56 to ~48.
//   LDS: Xs 16 KB + ushort list 2 KB = 18.4 KB -> 8 blocks fit (147 KB).
//   Per-wave in-flight unchanged (8 insts x 512B = 4 KB/step) -> total
//   in-flight doubles with waves. W/D logical traffic unchanged (tiles
//   partition cols). nt-D loads + nt stores retained (R12 win).
//   Accepted cost: X-broadcast ds_read_b128 has 4 kq-groups/wave -> 4-way
//   bank conflict (1.58x on 8 reads/step; small vs the memory stall).

typedef float f32x2 __attribute__((ext_vector_type(2)));

__device__ __forceinline__ f32x2 nt_load2(const float* p) {
    return __builtin_nontemporal_load((const f32x2*)p);
}
__device__ __forceinline__ void nt_store2(float* p, f32x2 v) {
    __builtin_nontemporal_store(v, (f32x2*)p);
}

__global__ __launch_bounds__(256, 8) void lms_fused_nt32(
    const float* __restrict__ X, const int* __restrict__ head_ix,
    const int* __restrict__ split_ix, const float* __restrict__ W,
    const float* __restrict__ D, const float* __restrict__ bias,
    float* __restrict__ out)
{
    constexpr int J    = 8;            // samples per chunk
    constexpr int KQ   = 16;           // k-split ways
    constexpr int KT   = IN_F / KQ;    // 32 k rows per thread
    constexpr int NST  = KT / 4;       // 8 steps of 4 rows

    __shared__ float buf[J * IN_F];        // Xs[8][512] <-> Red[16][8][16] f2
    __shared__ unsigned short list[N_SAMP];// 2 KB
    __shared__ int wsum[4];

    const int g    = blockIdx.y;           // combo = h*N_SPLITS + s
    const int h    = g >> 2;               // N_SPLITS == 4
    const int c0   = blockIdx.x * 32;      // 32-col tile
    const int tid  = threadIdx.x;
    const int c2   = tid & 15;             // col pair within tile
    const int kq   = tid >> 4;             // k-sixteenth (0..15)
    const int lane = tid & 63;
    const int wave = tid >> 6;

    // deterministic order-preserving compaction of samples matching combo g
    int run = 0;
    for (int r = 0; r < N_SAMP / 256; ++r) {
        const int i   = r * 256 + tid;
        const int key = head_ix[i] * N_SPLITS + split_ix[i];
        const bool hit = (key == g);
        const unsigned long long m = __ballot(hit);
        if (lane == 0) wsum[wave] = __popcll(m);
        __syncthreads();
        int base = run;
        for (int w = 0; w < 4; ++w)
            if (w < wave) base += wsum[w];
        if (hit)
            list[base + __popcll(m & ((1ULL << lane) - 1ULL))] =
                (unsigned short)i;
        run += wsum[0] + wsum[1] + wsum[2] + wsum[3];
        __syncthreads();               // wsum consumed before next round
    }
    const int total = run;
    if (total == 0) return;            // block-uniform

    // thread's stripes: rows kq*KT .. kq*KT+31, cols c0+2*c2 (+1)
    const size_t roff = (size_t)(kq * KT) * OUT_F + c0 + c2 * 2;
    const float* wp = W + (size_t)h * (IN_F * OUT_F) + roff;
    const float* dp = D + (size_t)g * (IN_F * OUT_F) + roff;

    for (int s0 = 0; s0 < total; s0 += J) {
        const int nc = min(total - s0, J);

        __syncthreads();               // buf may still hold previous Red
        // stage Xs: 1024 float4 over 256 threads = 4 each
#pragma unroll
        for (int f = 0; f < 4; ++f) {
            const int i = f * 256 + tid;       // 0..1023
            const int s = i >> 7, q = i & 127;
            float4 v = make_float4(0.f, 0.f, 0.f, 0.f);
            if (s < nc)
                v = *(const float4*)(X + (size_t)list[s0 + s] * IN_F + q * 4);
            *(float4*)(&buf[s * IN_F + q * 4]) = v;
        }
        __syncthreads();

        float2 acc[J];
#pragma unroll
        for (int j = 0; j < J; ++j) { acc[j].x = 0.f; acc[j].y = 0.f; }

        // distance-1 double-buffered 4-row batches: W cached, D nontemporal
        float2 wb[2][4];
        f32x2  db[2][4];
#pragma unroll
        for (int u = 0; u < 4; ++u) {
            wb[0][u] = *(const float2*)(wp + (size_t)u * OUT_F);
            db[0][u] = nt_load2(dp + (size_t)u * OUT_F);
        }

#pragma unroll 2
        for (int st = 0; st < NST; ++st) {
            // prefetch next 4-row batch (clamped tail keeps body branch-free)
            const int nx = (st + 1 < NST) ? st + 1 : NST - 1;
            const int nb = (st + 1) & 1, cb = st & 1;
            const float* wn = wp + (size_t)(nx * 4) * OUT_F;
            const float* dn = dp + (size_t)(nx * 4) * OUT_F;
#pragma unroll
            for (int u = 0; u < 4; ++u) {
                wb[nb][u] = *(const float2*)(wn + (size_t)u * OUT_F);
                db[nb][u] = nt_load2(dn + (size_t)u * OUT_F);
            }

            // combined weight for this 4-row batch
            float2 rc[4];
#pragma unroll
            for (int u = 0; u < 4; ++u) {
                rc[u].x = wb[cb][u].x + DELTA_SCALE * db[cb][u].x;
                rc[u].y = wb[cb][u].y + DELTA_SCALE * db[cb][u].y;
            }

            const float* xb = &buf[kq * KT + st * 4];
#pragma unroll
            for (int j = 0; j < J; ++j) {
                const float4 xv = *(const float4*)(xb + j * IN_F); // broadcast
                acc[j].x += xv.x * rc[0].x; acc[j].y += xv.x * rc[0].y;
                acc[j].x += xv.y * rc[1].x; acc[j].y += xv.y * rc[1].y;
                acc[j].x += xv.z * rc[2].x; acc[j].y += xv.z * rc[2].y;
                acc[j].x += xv.w * rc[3].x; acc[j].y += xv.w * rc[3].y;
            }
        }

        __syncthreads();               // Xs fully consumed; reuse buf as Red
        float2* Red = (float2*)buf;    // [KQ=16][J=8][16] f2 = 16 KB
#pragma unroll
        for (int j = 0; j < J; ++j)
            Red[(kq * J + j) * 16 + c2] = acc[j];
        __syncthreads();

        // sole-owner epilogue: 128 threads sum the 16 k-partials, add bias
        if (tid < 128) {
            const int j  = tid >> 4;       // 0..7
            const int cc = tid & 15;
            if (j < nc) {
                float2 s = make_float2(0.f, 0.f);
#pragma unroll
                for (int q = 0; q < KQ; ++q) {
                    const float2 r = Red[(q * J + j) * 16 + cc];
                    s.x += r.x; s.y += r.y;
                }
                const float2 bv =
                    *(const float2*)(bias + (size_t)h * OUT_F + c0 + cc * 2);
                float* op = out + (size_t)list[s0 + j] * OUT_F + c0 + cc * 2;
                f32x2 res;
                res.x = s.x + bv.x;
                res.y = s.y + bv.y;
                nt_store2(op, res);
            }
        }
    }
}

extern "C" void kernel_launch(void* const* d_in, const int* in_sizes, int n_in,
                              void* d_out, int out_size, void* d_ws, size_t ws_size,
                              hipStream_t stream) {
    const float* X        = (const float*)d_in[0];
    const int*   head_ix  = (const int*)d_in[1];
    const int*   split_ix = (const int*)d_in[2];
    const float* W        = (const float*)d_in[3];
    const float* D        = (const float*)d_in[4];
    const float* bias     = (const float*)d_in[5];
    float*       out      = (float*)d_out;

    // 128 combos x 16 col-tiles = 2048 blocks of 256 thr = 8 blocks/CU
    // (18.4 KB LDS) x 4 waves = 32 waves/CU. VGPR capped at 64 by
    // launch_bounds(256,8) -- J=8 fits (~48 est vs R12's measured 56 at
    // J=16). Single dispatch; out written exactly once, bias folded.
    dim3 gf(OUT_F / 32, N_GROUPS);
    lms_fused_nt32<<<gf, 256, 0, stream>>>(X, head_ix, split_ix, W, D, bias, out);
}

// Round 11
// 246.736 us; speedup vs baseline: 1.8770x; 1.2497x over previous
//
#include <hip/hip_runtime.h>

#define N_SAMP   1024
#define IN_F     512
#define OUT_F    512
#define N_HEADS  32
#define N_SPLITS 4
#define N_GROUPS (N_HEADS * N_SPLITS)
#define DELTA_SCALE 0.1f

// R15 (resubmit; R10's bench was an infra failure, not a kernel failure):
// R14 structure with __launch_bounds__(256, 4) -- the ONE-TOKEN fix.
//
// Empirical law pinned across R7/R8/R9/R10/R12/R13/R14: this toolchain's
// VGPR cap = 256 / arg2  (2->128, 4->64, 8->32). R13/R14's arg2=8 forced a
// 32-VGPR cap -> accumulator spills (69-455 MB scratch traffic) -- both
// "32 waves/CU" experiments were confounded. arg2=4 caps at exactly 64 =
// the 8-waves/SIMD boundary (8 x 64 = 512 pool), and the declared minimum
// is a floor for the allocator, NOT a runtime occupancy ceiling: with
// LDS 18.4 KB (8 blocks/CU) and VGPR <= 64, hardware can co-res
// 8 blocks x 4 waves = 32 waves/CU. This finally runs the wave-scaling
// test (8 waves/CU -> 1.7 TB/s; 16 -> 3.5 TB/s; 32 -> ?) un-confounded.
//
//   grid = 16 col-tiles x 128 combos = 2048 blocks of 256 thr.
//   thread = (c2 = tid&15: col pair in 32-col tile, kq = tid>>4: KQ=16,
//   KT=32, NST=8). J=8 (mean combo = 8 samples -> 1 chunk typical).
//   nt-D loads + nt stores retained (R12 win); W cached (4x L2 reuse),
//   X cached (16 col-tile blocks share rows via L2/L3).
//   Accepted cost: X-broadcast ds_read_b128 has 4 kq-groups/wave -> 4-way
//   bank conflict (~1.58x on 8 reads/step; small vs the memory stall).

typedef float f32x2 __attribute__((ext_vector_type(2)));

__device__ __forceinline__ f32x2 nt_load2(const float* p) {
    return __builtin_nontemporal_load((const f32x2*)p);
}
__device__ __forceinline__ void nt_store2(float* p, f32x2 v) {
    __builtin_nontemporal_store(v, (f32x2*)p);
}

__global__ __launch_bounds__(256, 4) void lms_fused_nt32(
    const float* __restrict__ X, const int* __restrict__ head_ix,
    const int* __restrict__ split_ix, const float* __restrict__ W,
    const float* __restrict__ D, const float* __restrict__ bias,
    float* __restrict__ out)
{
    constexpr int J    = 8;            // samples per chunk
    constexpr int KQ   = 16;           // k-split ways
    constexpr int KT   = IN_F / KQ;    // 32 k rows per thread
    constexpr int NST  = KT / 4;       // 8 steps of 4 rows

    __shared__ float buf[J * IN_F];        // Xs[8][512] <-> Red[16][8][16] f2
    __shared__ unsigned short list[N_SAMP];// 2 KB
    __shared__ int wsum[4];

    const int g    = blockIdx.y;           // combo = h*N_SPLITS + s
    const int h    = g >> 2;               // N_SPLITS == 4
    const int c0   = blockIdx.x * 32;      // 32-col tile
    const int tid  = threadIdx.x;
    const int c2   = tid & 15;             // col pair within tile
    const int kq   = tid >> 4;             // k-sixteenth (0..15)
    const int lane = tid & 63;
    const int wave = tid >> 6;

    // deterministic order-preserving compaction of samples matching combo g
    int run = 0;
    for (int r = 0; r < N_SAMP / 256; ++r) {
        const int i   = r * 256 + tid;
        const int key = head_ix[i] * N_SPLITS + split_ix[i];
        const bool hit = (key == g);
        const unsigned long long m = __ballot(hit);
        if (lane == 0) wsum[wave] = __popcll(m);
        __syncthreads();
        int base = run;
        for (int w = 0; w < 4; ++w)
            if (w < wave) base += wsum[w];
        if (hit)
            list[base + __popcll(m & ((1ULL << lane) - 1ULL))] =
                (unsigned short)i;
        run += wsum[0] + wsum[1] + wsum[2] + wsum[3];
        __syncthreads();               // wsum consumed before next round
    }
    const int total = run;
    if (total == 0) return;            // block-uniform

    // thread's stripes: rows kq*KT .. kq*KT+31, cols c0+2*c2 (+1)
    const size_t roff = (size_t)(kq * KT) * OUT_F + c0 + c2 * 2;
    const float* wp = W + (size_t)h * (IN_F * OUT_F) + roff;
    const float* dp = D + (size_t)g * (IN_F * OUT_F) + roff;

    for (int s0 = 0; s0 < total; s0 += J) {
        const int nc = min(total - s0, J);

        __syncthreads();               // buf may still hold previous Red
        // stage Xs: 1024 float4 over 256 threads = 4 each
#pragma unroll
        for (int f = 0; f < 4; ++f) {
            const int i = f * 256 + tid;       // 0..1023
            const int s = i >> 7, q = i & 127;
            float4 v = make_float4(0.f, 0.f, 0.f, 0.f);
            if (s < nc)
                v = *(const float4*)(X + (size_t)list[s0 + s] * IN_F + q * 4);
            *(float4*)(&buf[s * IN_F + q * 4]) = v;
        }
        __syncthreads();

        float2 acc[J];
#pragma unroll
        for (int j = 0; j < J; ++j) { acc[j].x = 0.f; acc[j].y = 0.f; }

        // distance-1 double-buffered 4-row batches: W cached, D nontemporal
        float2 wb[2][4];
        f32x2  db[2][4];
#pragma unroll
        for (int u = 0; u < 4; ++u) {
            wb[0][u] = *(const float2*)(wp + (size_t)u * OUT_F);
            db[0][u] = nt_load2(dp + (size_t)u * OUT_F);
        }

#pragma unroll 2
        for (int st = 0; st < NST; ++st) {
            // prefetch next 4-row batch (clamped tail keeps body branch-free)
            const int nx = (st + 1 < NST) ? st + 1 : NST - 1;
            const int nb = (st + 1) & 1, cb = st & 1;
            const float* wn = wp + (size_t)(nx * 4) * OUT_F;
            const float* dn = dp + (size_t)(nx * 4) * OUT_F;
#pragma unroll
            for (int u = 0; u < 4; ++u) {
                wb[nb][u] = *(const float2*)(wn + (size_t)u * OUT_F);
                db[nb][u] = nt_load2(dn + (size_t)u * OUT_F);
            }

            // combined weight for this 4-row batch
            float2 rc[4];
#pragma unroll
            for (int u = 0; u < 4; ++u) {
                rc[u].x = wb[cb][u].x + DELTA_SCALE * db[cb][u].x;
                rc[u].y = wb[cb][u].y + DELTA_SCALE * db[cb][u].y;
            }

            const float* xb = &buf[kq * KT + st * 4];
#pragma unroll
            for (int j = 0; j < J; ++j) {
                const float4 xv = *(const float4*)(xb + j * IN_F); // broadcast
                acc[j].x += xv.x * rc[0].x; acc[j].y += xv.x * rc[0].y;
                acc[j].x += xv.y * rc[1].x; acc[j].y += xv.y * rc[1].y;
                acc[j].x += xv.z * rc[2].x; acc[j].y += xv.z * rc[2].y;
                acc[j].x += xv.w * rc[3].x; acc[j].y += xv.w * rc[3].y;
            }
        }

        __syncthreads();               // Xs fully consumed; reuse buf as Red
        float2* Red = (float2*)buf;    // [KQ=16][J=8][16] f2 = 16 KB
#pragma unroll
        for (int j = 0; j < J; ++j)
            Red[(kq * J + j) * 16 + c2] = acc[j];
        __syncthreads();

        // sole-owner epilogue: 128 threads sum the 16 k-partials, add bias
        if (tid < 128) {
            const int j  = tid >> 4;       // 0..7
            const int cc = tid & 15;
            if (j < nc) {
                float2 s = make_float2(0.f, 0.f);
#pragma unroll
                for (int q = 0; q < KQ; ++q) {
                    const float2 r = Red[(q * J + j) * 16 + cc];
                    s.x += r.x; s.y += r.y;
                }
                const float2 bv =
                    *(const float2*)(bias + (size_t)h * OUT_F + c0 + cc * 2);
                float* op = out + (size_t)list[s0 + j] * OUT_F + c0 + cc * 2;
                f32x2 res;
                res.x = s.x + bv.x;
                res.y = s.y + bv.y;
                nt_store2(op, res);
            }
        }
    }
}

extern "C" void kernel_launch(void* const* d_in, const int* in_sizes, int n_in,
                              void* d_out, int out_size, void* d_ws, size_t ws_size,
                              hipStream_t stream) {
    const float* X        = (const float*)d_in[0];
    const int*   head_ix  = (const int*)d_in[1];
    const int*   split_ix = (const int*)d_in[2];
    const float* W        = (const float*)d_in[3];
    const float* D        = (const float*)d_in[4];
    const float* bias     = (const float*)d_in[5];
    float*       out      = (float*)d_out;

    // 128 combos x 16 col-tiles = 2048 blocks of 256 thr. LDS 18.4 KB ->
    // 8 blocks/CU eligible; launch_bounds(256,4) -> VGPR cap 64 = the
    // 8-waves/SIMD boundary, so hardware can reach 32 waves/CU without
    // spills. Single dispatch; out written exactly once, bias folded.
    dim3 gf(OUT_F / 32, N_GROUPS);
    lms_fused_nt32<<<gf, 256, 0, stream>>>(X, head_ix, split_ix, W, D, bias, out);
}